// Round 17
// baseline (142.388 us; speedup 1.0000x reference)
//
#include <hip/hip_runtime.h>
#include <math.h>

constexpr int Bn  = 2;
constexpr int Cn  = 128;
constexpr int Hn  = 96;
constexpr int Wn  = 96;
constexpr int HWn = Hn * Wn;        // 9216
constexpr int CHWn = Cn * HWn;      // 1179648
constexpr int KCn = Cn * 9;         // 1152
constexpr float EPSn = 1e-5f;
constexpr int PXB  = 32;            // pixels per block
constexpr int KPAD = 1160;          // S row stride in shorts (2320B)

typedef short bf16x8 __attribute__((ext_vector_type(8)));
typedef float f32x4  __attribute__((ext_vector_type(4)));

static __device__ inline short f2bf(float f) {
    union { float f; unsigned u; } v; v.f = f;
    unsigned r = v.u + 0x7fff + ((v.u >> 16) & 1);
    return (short)(r >> 16);
}
static __device__ inline unsigned pack2(float a, float b) {
    unsigned r;
    asm("v_cvt_pk_bf16_f32 %0, %1, %2" : "=v"(r) : "v"(a), "v"(b));
    return r;
}

// Fragment-shuffled dconv weights, all 3 stages.
// wbs[stage][((g*36 + j)*64 + l)*8 + e]: row o=g*16+(l&15), kidx=j*32+(l>>4)*8+e
__global__ __launch_bounds__(256) void cvt_w_all(
    const float* __restrict__ w1, const float* __restrict__ w2,
    const float* __restrict__ w3, short* __restrict__ wbs)
{
    const int bid = blockIdx.x;               // 3*576
    const int stage = bid / 576;
    const float* w = (stage == 0) ? w1 : (stage == 1) ? w2 : w3;
    int t = (bid - stage * 576) * 256 + threadIdx.x;
    int e = t & 7, l = (t >> 3) & 63, rest = t >> 9;   // rest 0..287
    int j = rest % 36, g = rest / 36;
    int lr = l & 15, lq = l >> 4;
    int o = g * 16 + lr;
    int kidx = j * 32 + lq * 8 + e;
    int k = kidx >> 7, c = kidx & 127;
    wbs[stage * Cn * KCn + t] = f2bf(w[o * KCn + c * 9 + k]);
}

// j-ordered fragment-shuffled offconv weights (2 mh halves of M=32).
__global__ __launch_bounds__(256) void cvt_ow_all(
    const float* __restrict__ w1, const float* __restrict__ w2,
    const float* __restrict__ w3, short* __restrict__ owbs)
{
    const int bid = blockIdx.x;               // 3*144
    const int stage = bid / 144;
    const float* ow = (stage == 0) ? w1 : (stage == 1) ? w2 : w3;
    int t = (bid - stage * 144) * 256 + threadIdx.x;
    int e = t & 7, l = (t >> 3) & 63, rest = t >> 9;   // rest 0..71
    int j = rest % 36, mh = rest / 36;
    int lr = l & 15, lq = l >> 4;
    int o = mh * 16 + lr;
    int kidx = j * 32 + lq * 8 + e;
    int k = kidx >> 7, c = kidx & 127;
    owbs[stage * 32 * KCn + t] = (o < 27) ? f2bf(ow[o * KCn + c * 9 + k]) : (short)0;
}

// NCHW -> NHWC, dual output: f32 (residual-exact) + bf16 (gather path)
__global__ __launch_bounds__(256) void nchw2nhwc(
    const float* __restrict__ x, float* __restrict__ xTf,
    unsigned short* __restrict__ xTb)
{
    __shared__ float Tl[128][65];
    const int t = threadIdx.x;
    const int pix0 = blockIdx.x * 64;
    const int b   = pix0 / HWn;
    const int sp0 = pix0 - b * HWn;
    const float* xb = x + b * CHWn + sp0 + (t & 63);
    const int c0 = t >> 6;
#pragma unroll 8
    for (int i = 0; i < 32; ++i) {
        const int c = c0 + 4 * i;
        Tl[c][t & 63] = xb[c * HWn];
    }
    __syncthreads();
    float* dstf = xTf + pix0 * 128;
    unsigned short* dstb = xTb + pix0 * 128;
#pragma unroll 8
    for (int i = 0; i < 32; ++i) {
        const int o = t + 256 * i;
        float v = Tl[o & 127][o >> 7];
        dstf[o] = v;
        dstb[o] = (unsigned short)f2bf(v);
    }
}

// One fused residual block: 32 px / 1024 threads (16 waves), NHWC bf16 gathers,
// LDS-free offconv (shifted-pixel B-frags), dconv K-split across wave pairs.
__global__ __launch_bounds__(1024, 8) void fused_stage(
    const unsigned short* __restrict__ xTb, const float* __restrict__ xTf,
    const short* __restrict__ wbs, const short* __restrict__ owbs,
    const float* __restrict__ obv,
    const float* __restrict__ gv, const float* __restrict__ bv,
    const float* __restrict__ mv, const float* __restrict__ vv,
    float* __restrict__ outTf, unsigned short* __restrict__ outTb,
    float* __restrict__ outC, int dil, int last)
{
    __shared__ short S[PXB * KPAD];           // 74240B: bil im2col / reduce / O
    __shared__ float offL[PXB][18];
    __shared__ float maskL[PXB][9];

    const int t   = threadIdx.x;
    const int l   = t & 63;
    const int wv  = t >> 6;                   // wave 0..15
    const int lr  = l & 15, lq = l >> 4;

    // XCD-aware bijective swizzle: 576 blocks = 8 XCDs x 72 contiguous
    const int bid = blockIdx.x;
    const int swz = (bid & 7) * 72 + (bid >> 3);
    const int pix0 = swz * PXB;               // 96%32==0: never crosses a row
    const int b   = pix0 / HWn;
    const int sp0 = pix0 - b * HWn;
    const int hy  = sp0 / Wn;
    const int wx0 = sp0 - hy * Wn;
    const int basep = b * HWn;

    // ======== offconv, LDS-free: wave = (mh, pxf, kg) ========
    const int mh = wv & 1, pxf = (wv >> 1) & 1, kg = wv >> 2;
    const int tap0 = kg * 2;
    const int tapn = (kg == 3) ? 3 : 2;
    f32x4 oacc = {0.f, 0.f, 0.f, 0.f};
    const bf16x8 bz = {0, 0, 0, 0, 0, 0, 0, 0};
    for (int tt = 0; tt < tapn; ++tt) {       // wave-uniform count (2 or 3)
        const int k = tap0 + tt;
        const int iy = hy + (k / 3 - 1) * dil;
        const bool yv = (iy >= 0) && (iy < Hn);
        const int ix = wx0 + pxf * 16 + lr + (k % 3 - 1) * dil;
        const bool v = yv && (ix >= 0) && (ix < Wn);
        const int ixc = min(max(ix, 0), Wn - 1);
        const unsigned short* bp =
            xTb + (basep + (yv ? iy : 0) * Wn + ixc) * 128 + lq * 8;
        const short* arow = owbs + (mh * 36 + k * 4) * 512 + l * 8;
#pragma unroll
        for (int s = 0; s < 4; ++s) {
            bf16x8 raw = *(const bf16x8*)(bp + s * 32);
            bf16x8 bfv = v ? raw : bz;
            bf16x8 af  = *(const bf16x8*)(arow + s * 512);
            oacc = __builtin_amdgcn_mfma_f32_16x16x32_bf16(af, bfv, oacc, 0, 0, 0);
        }
    }
    {   // reduce over kg (4-way): red slot = kg*4 + mh*2 + pxf
        float* red = (float*)S;               // 16KB alias (S not yet used)
        *(f32x4*)&red[(kg * 4 + mh * 2 + pxf) * 256 + l * 4] = oacc;
    }
    __syncthreads();
    if (wv < 4) {
        const int m2 = wv & 1, pf2 = wv >> 1;
        const float* red = (const float*)S;
        f32x4 sm = {0.f, 0.f, 0.f, 0.f};
#pragma unroll
        for (int g = 0; g < 4; ++g)
            sm += *(const f32x4*)&red[(g * 4 + m2 * 2 + pf2) * 256 + l * 4];
        const int px = pf2 * 16 + lr;
#pragma unroll
        for (int r = 0; r < 4; ++r) {
            int oc = m2 * 16 + lq * 4 + r;
            if (oc < 18) {
                offL[px][oc] = sm[r] + obv[oc];
            } else if (oc < 27) {
                float z = sm[r] + obv[oc];
                maskL[px][oc - 18] = 1.f / (1.f + expf(-z));
            }
        }
    }
    __syncthreads();                           // offL/maskL ready; red dead

    // ---- bilinear params: lane j(<18) -> (pp=wv*2+j/9, k=j%9), 16 waves=32px ----
    int pw0i = 0, pw1i = 0, pw2i = 0, pw3i = 0, pa0 = 0, pa1 = 0, pdx = 0;
    if (l < 18) {
        const int p = wv * 2 + l / 9;
        const int k = l - 9 * (l / 9);
        const float offy = offL[p][2 * k];
        const float offx = offL[p][2 * k + 1];
        const float m    = maskL[p][k];
        const float py = (float)(hy + (k / 3 - 1) * dil) + offy;
        const float px = (float)(wx0 + p + (k % 3 - 1) * dil) + offx;
        const float y0f = floorf(py), x0f = floorf(px);
        const float ly = py - y0f, lx = px - x0f;
        const int y0 = (int)y0f, x0 = (int)x0f;
        const float yv0 = (y0 >= 0 && y0 < Hn)      ? 1.f : 0.f;
        const float yv1 = (y0 >= -1 && y0 < Hn - 1) ? 1.f : 0.f;
        const float xv0 = (x0 >= 0 && x0 < Wn)      ? 1.f : 0.f;
        const float xv1 = (x0 >= -1 && x0 < Wn - 1) ? 1.f : 0.f;
        const float wy0 = (1.f - ly) * yv0 * m;
        const float wy1 = ly * yv1 * m;
        const float wxa = (1.f - lx) * xv0;
        const float wxb = lx * xv1;
        pw0i = __float_as_int(wy0 * wxa);
        pw1i = __float_as_int(wy0 * wxb);
        pw2i = __float_as_int(wy1 * wxa);
        pw3i = __float_as_int(wy1 * wxb);
        const int y0c = min(max(y0, 0), Hn - 1), y1c = min(max(y0 + 1, 0), Hn - 1);
        const int x0c = min(max(x0, 0), Wn - 1), x1c = min(max(x0 + 1, 0), Wn - 1);
        pa0 = (basep + y0c * Wn + x0c) * 128;
        pa1 = (basep + y1c * Wn + x1c) * 128;
        pdx = (x1c - x0c) * 128;
    }

    // ---- gather-bil: 18 (px,tap) iters/wave, 6 batches x 3 ----
#pragma unroll
    for (int bch = 0; bch < 6; ++bch) {
        unsigned u00[3], u01[3], u10[3], u11[3];
        float    w00[3], w01[3], w10[3], w11[3];
#pragma unroll
        for (int u = 0; u < 3; ++u) {
            const int i = bch * 3 + u;
            w00[u] = __int_as_float(__builtin_amdgcn_readlane(pw0i, i));
            w01[u] = __int_as_float(__builtin_amdgcn_readlane(pw1i, i));
            w10[u] = __int_as_float(__builtin_amdgcn_readlane(pw2i, i));
            w11[u] = __int_as_float(__builtin_amdgcn_readlane(pw3i, i));
            const int a00 = __builtin_amdgcn_readlane(pa0, i);
            const int a11 = __builtin_amdgcn_readlane(pa1, i);
            const int dxk = __builtin_amdgcn_readlane(pdx, i);
            const unsigned short* xp = xTb + a00;
            const unsigned short* xq = xTb + a11;
            u00[u] = ((const unsigned*)xp)[l];
            u01[u] = ((const unsigned*)(xp + dxk))[l];
            u10[u] = ((const unsigned*)(xq - dxk))[l];
            u11[u] = ((const unsigned*)xq)[l];
        }
#pragma unroll
        for (int u = 0; u < 3; ++u) {
            const int i  = bch * 3 + u;
            const int di = i / 9;
            const int k  = i - di * 9;
            const int pp = wv * 2 + di;
            const float f00a = __int_as_float(u00[u] << 16);
            const float f00b = __int_as_float(u00[u] & 0xffff0000u);
            const float f01a = __int_as_float(u01[u] << 16);
            const float f01b = __int_as_float(u01[u] & 0xffff0000u);
            const float f10a = __int_as_float(u10[u] << 16);
            const float f10b = __int_as_float(u10[u] & 0xffff0000u);
            const float f11a = __int_as_float(u11[u] << 16);
            const float f11b = __int_as_float(u11[u] & 0xffff0000u);
            float s0 = w00[u] * f00a + w01[u] * f01a + w10[u] * f10a + w11[u] * f11a;
            float s1 = w00[u] * f00b + w01[u] * f01b + w10[u] * f10b + w11[u] * f11b;
            ((unsigned*)&S[pp * KPAD + k * 128])[l] = pack2(s0, s1);
        }
    }
    __syncthreads();

    // ---- dconv GEMM: wave = (ocg 8, khf 2); A reused over 2 px-cols ----
    const int ocg = wv & 7, khf = wv >> 3;
    f32x4 dacc0 = {0.f,0.f,0.f,0.f}, dacc1 = {0.f,0.f,0.f,0.f};
    {
        const short* darow = wbs + (ocg * 36 + khf * 18) * 512 + l * 8;
        const short* sr0   = &S[lr * KPAD + khf * 18 * 32 + lq * 8];
        const short* sr1   = &S[(16 + lr) * KPAD + khf * 18 * 32 + lq * 8];
#pragma unroll
        for (int bch = 0; bch < 3; ++bch) {
            bf16x8 af[6], bf0[6], bf1[6];
#pragma unroll
            for (int u = 0; u < 6; ++u) af[u]  = *(const bf16x8*)(darow + (bch * 6 + u) * 512);
#pragma unroll
            for (int u = 0; u < 6; ++u) bf0[u] = *(const bf16x8*)(sr0 + (bch * 6 + u) * 32);
#pragma unroll
            for (int u = 0; u < 6; ++u) bf1[u] = *(const bf16x8*)(sr1 + (bch * 6 + u) * 32);
#pragma unroll
            for (int u = 0; u < 6; ++u) {
                dacc0 = __builtin_amdgcn_mfma_f32_16x16x32_bf16(af[u], bf0[u], dacc0, 0, 0, 0);
                dacc1 = __builtin_amdgcn_mfma_f32_16x16x32_bf16(af[u], bf1[u], dacc1, 0, 0, 0);
            }
        }
    }
    __syncthreads();                           // S(bil) reads done
    {   // K-half reduce staging: slot = (khf*8+ocg)*2 + pxc, 32KB alias on S
        float* red2 = (float*)S;
        *(f32x4*)&red2[((khf * 8 + ocg) * 2 + 0) * 256 + l * 4] = dacc0;
        *(f32x4*)&red2[((khf * 8 + ocg) * 2 + 1) * 256 + l * 4] = dacc1;
    }
    __syncthreads();

    // ---- final: wave = (ocg2 8, pxc2 2): sum K-halves, BN+ReLU+residual ----
    const int ocg2 = wv & 7, pxc2 = wv >> 3;
    const float* red2 = (const float*)S;
    f32x4 da = *(const f32x4*)&red2[((0 * 8 + ocg2) * 2 + pxc2) * 256 + l * 4];
    f32x4 db = *(const f32x4*)&red2[((1 * 8 + ocg2) * 2 + pxc2) * 256 + l * 4];
    f32x4 dsum = da + db;
    const int px  = pxc2 * 16 + lr;
    const int ocb = ocg2 * 16 + lq * 4;
    if (last) {
#pragma unroll
        for (int r = 0; r < 4; ++r) {
            const int oc = ocb + r;
            const float sc = gv[oc] * rsqrtf(vv[oc] + EPSn);
            float y = (dsum[r] - mv[oc]) * sc + bv[oc];
            y = fmaxf(y, 0.f);
            y += xTf[(pix0 + px) * 128 + oc];
            outC[b * CHWn + oc * HWn + sp0 + px] = y;
        }
    } else {
        float* O = (float*)S + 8192;           // 32KB offset: disjoint from red2
        f32x4 y;
#pragma unroll
        for (int r = 0; r < 4; ++r) {
            const int oc = ocb + r;
            const float sc = gv[oc] * rsqrtf(vv[oc] + EPSn);
            y[r] = fmaxf((dsum[r] - mv[oc]) * sc + bv[oc], 0.f);
        }
        *(f32x4*)&O[px * 132 + ocb] = y;
        __syncthreads();
        const int o  = t * 4;                  // 0..4095
        const int qp = o >> 7, qc = o & 127;
        f32x4 yv = *(f32x4*)&O[qp * 132 + qc];
        f32x4 rv = *(const f32x4*)&xTf[(pix0 + qp) * 128 + qc];
        yv += rv;
        *(f32x4*)&outTf[(pix0 + qp) * 128 + qc] = yv;
        uint2 pk;
        pk.x = pack2(yv[0], yv[1]);
        pk.y = pack2(yv[2], yv[3]);
        *(uint2*)&outTb[(pix0 + qp) * 128 + qc] = pk;
    }
}

extern "C" void kernel_launch(void* const* d_in, const int* in_sizes, int n_in,
                              void* d_out, int out_size, void* d_ws, size_t ws_size,
                              hipStream_t stream) {
    (void)in_sizes; (void)n_in; (void)out_size; (void)ws_size;

    const float* hu = (const float*)d_in[0];

    short* wbs  = (short*)d_ws;                          // 3 * 147456 shorts
    short* owbs = wbs + 3 * Cn * KCn;                    // 3 * 36864 shorts
    unsigned short* T0b = (unsigned short*)(owbs + 3 * 32 * KCn);  // Bn*CHWn
    unsigned short* T1b = T0b + Bn * CHWn;
    float* T0f = (float*)(T1b + Bn * CHWn);
    float* T1f = T0f + Bn * CHWn;

    cvt_w_all<<<3 * 576, 256, 0, stream>>>(
        (const float*)d_in[3], (const float*)d_in[10], (const float*)d_in[17], wbs);
    cvt_ow_all<<<3 * 144, 256, 0, stream>>>(
        (const float*)d_in[1], (const float*)d_in[8], (const float*)d_in[15], owbs);

    nchw2nhwc<<<(Bn * HWn) / 64, 256, 0, stream>>>(hu, T0f, T0b);

    const int dils[3] = {2, 4, 8};
    const unsigned short* insb[3] = {T0b, T1b, T0b};
    const float*          insf[3] = {T0f, T1f, T0f};
    float*          outsf[3] = {T1f, T0f, nullptr};
    unsigned short* outsb[3] = {T1b, T0b, nullptr};
    const int nblk = (Bn * HWn) / PXB;            // 576

    for (int i = 0; i < 3; ++i) {
        const float* obv = (const float*)d_in[2 + 7 * i];
        const float* gv  = (const float*)d_in[4 + 7 * i];
        const float* bv  = (const float*)d_in[5 + 7 * i];
        const float* mv  = (const float*)d_in[6 + 7 * i];
        const float* vv  = (const float*)d_in[7 + 7 * i];
        const int last = (i == 2);

        fused_stage<<<nblk, 1024, 0, stream>>>(
            insb[i], insf[i], wbs + i * Cn * KCn, owbs + i * 32 * KCn, obv,
            gv, bv, mv, vv, outsf[i], outsb[i],
            last ? (float*)d_out : nullptr, dils[i], last);
    }
}

// Round 18
// 114.076 us; speedup vs baseline: 1.2482x; 1.2482x over previous
//
#include <hip/hip_runtime.h>
#include <math.h>

constexpr int Bn  = 2;
constexpr int Cn  = 128;
constexpr int Hn  = 96;
constexpr int Wn  = 96;
constexpr int HWn = Hn * Wn;        // 9216
constexpr int CHWn = Cn * HWn;      // 1179648
constexpr int KCn = Cn * 9;         // 1152
constexpr float EPSn = 1e-5f;
constexpr int KPAD = 1160;          // LDS row stride in shorts (2320B)

typedef short bf16x8 __attribute__((ext_vector_type(8)));
typedef float f32x4  __attribute__((ext_vector_type(4)));

static __device__ inline short f2bf(float f) {
    union { float f; unsigned u; } v; v.f = f;
    unsigned r = v.u + 0x7fff + ((v.u >> 16) & 1);
    return (short)(r >> 16);
}
static __device__ inline unsigned pack2(float a, float b) {
    unsigned r;
    asm("v_cvt_pk_bf16_f32 %0, %1, %2" : "=v"(r) : "v"(a), "v"(b));
    return r;
}

// Fragment-shuffled dconv weights, 3 stages in one launch (r14 mapping).
__global__ __launch_bounds__(256) void cvt_w_all(
    const float* __restrict__ w1, const float* __restrict__ w2,
    const float* __restrict__ w3, short* __restrict__ wbs)
{
    const int bid = blockIdx.x;               // 3*576
    const int stage = bid / 576;
    const float* w = (stage == 0) ? w1 : (stage == 1) ? w2 : w3;
    int t = (bid - stage * 576) * 256 + threadIdx.x;
    int e = t & 7, l = (t >> 3) & 63, rest = t >> 9;   // rest 0..287
    int j = rest % 36, g = rest / 36;
    int lr = l & 15, lq = l >> 4;
    int o = g * 16 + lr;
    int kidx = j * 32 + lq * 8 + e;
    int k = kidx >> 7, c = kidx & 127;
    wbs[stage * Cn * KCn + t] = f2bf(w[o * KCn + c * 9 + k]);
}

// Fragment-shuffled offconv weights, 3 stages (r14 mapping: wvv=(mh,ks)).
__global__ __launch_bounds__(256) void cvt_ow_all(
    const float* __restrict__ w1, const float* __restrict__ w2,
    const float* __restrict__ w3, short* __restrict__ owbs)
{
    const int bid = blockIdx.x;               // 3*144
    const int stage = bid / 144;
    const float* ow = (stage == 0) ? w1 : (stage == 1) ? w2 : w3;
    int t = (bid - stage * 144) * 256 + threadIdx.x;
    int e = t & 7, l = (t >> 3) & 63, rest = t >> 9;   // rest 0..71
    int kk = rest % 9, wvv = rest / 9;
    int mh = wvv & 1, ks = wvv >> 1;
    int lr = l & 15, lq = l >> 4;
    int o = mh * 16 + lr;
    int kidx = ks * 288 + kk * 32 + lq * 8 + e;
    int k = kidx >> 7, c = kidx & 127;
    owbs[stage * 32 * KCn + t] = (o < 27) ? f2bf(ow[o * KCn + c * 9 + k]) : (short)0;
}

// NCHW -> NHWC, dual output: f32 (residual-exact) + bf16 (gather path)
__global__ __launch_bounds__(256) void nchw2nhwc(
    const float* __restrict__ x, float* __restrict__ xTf,
    unsigned short* __restrict__ xTb)
{
    __shared__ float Tl[128][65];
    const int t = threadIdx.x;
    const int pix0 = blockIdx.x * 64;
    const int b   = pix0 / HWn;
    const int sp0 = pix0 - b * HWn;
    const float* xb = x + b * CHWn + sp0 + (t & 63);
    const int c0 = t >> 6;
#pragma unroll 8
    for (int i = 0; i < 32; ++i) {
        const int c = c0 + 4 * i;
        Tl[c][t & 63] = xb[c * HWn];
    }
    __syncthreads();
    float* dstf = xTf + pix0 * 128;
    unsigned short* dstb = xTb + pix0 * 128;
#pragma unroll 8
    for (int i = 0; i < 32; ++i) {
        const int o = t + 256 * i;
        float v = Tl[o & 127][o >> 7];
        dstf[o] = v;
        dstb[o] = (unsigned short)f2bf(v);
    }
}

// One fused residual block, 16 pixels / 512 threads, NHWC bf16 gathers,
// f32 residual, fragment-shuffled weights, cross-barrier A-frag prefetch.
__global__ __launch_bounds__(512, 6) void fused_stage(
    const unsigned short* __restrict__ xTb, const float* __restrict__ xTf,
    const short* __restrict__ wbs, const short* __restrict__ owbs,
    const float* __restrict__ obv,
    const float* __restrict__ gv, const float* __restrict__ bv,
    const float* __restrict__ mv, const float* __restrict__ vv,
    float* __restrict__ outTf, unsigned short* __restrict__ outTb,
    float* __restrict__ outC, int dil, int last)
{
    __shared__ short S[16 * KPAD];            // im2col tile S[p][K'], 37120B
    __shared__ float offL[16][18];
    __shared__ float maskL[16][9];

    const int t   = threadIdx.x;
    const int l   = t & 63;
    const int wv  = t >> 6;                   // wave 0..7
    const int lh  = l >> 5;                   // pixel half (gather-int)
    const int lc  = l & 31;                   // channel quad (gather-int)

    // XCD-aware bijective swizzle: 1152 blocks = 8 XCDs x 144 contiguous
    const int bid = blockIdx.x;
    const int swz = (bid & 7) * 144 + (bid >> 3);
    const int pix0 = swz * 16;
    const int b   = pix0 / HWn;
    const int sp0 = pix0 - b * HWn;
    const int hy  = sp0 / Wn;
    const int wx0 = sp0 - hy * Wn;
    const int basep = b * HWn;

    // ---- prefetch offconv A-frags (consumed after the barrier) ----
    bf16x8 oaf[9];
    {
        const short* oarow = owbs + (wv * 9) * 512 + l * 8;
#pragma unroll
        for (int u = 0; u < 9; ++u) oaf[u] = *(const bf16x8*)(oarow + u * 512);
    }

    // ---- gather-int: bf16 source, pure masked copy (uint2 = 4ch) ----
#pragma unroll
    for (int bch = 0; bch < 3; ++bch) {
        uint2 vle[3];
#pragma unroll
        for (int u = 0; u < 3; ++u) {
            const int k  = bch * 3 + u;
            const int pp = wv * 2 + lh;
            const int iy = hy + (k / 3 - 1) * dil;
            const int ix = wx0 + pp + (k % 3 - 1) * dil;
            const bool v = (iy >= 0) && (iy < Hn) && (ix >= 0) && (ix < Wn);
            const int aof = v ? (basep + iy * Wn + ix) : basep;
            uint2 val = ((const uint2*)(xTb + aof * 128))[lc];
            vle[u].x = v ? val.x : 0u;
            vle[u].y = v ? val.y : 0u;
        }
#pragma unroll
        for (int u = 0; u < 3; ++u) {
            const int k  = bch * 3 + u;
            const int pp = wv * 2 + lh;
            ((uint2*)&S[pp * KPAD + k * 128])[lc] = vle[u];
        }
    }
    __syncthreads();

    // ---- offconv GEMM: A from prefetched regs, B from S ----
    f32x4 oacc = {0.f, 0.f, 0.f, 0.f};
    {
        const int ks = wv >> 1;
        const short* srow = &S[(l & 15) * KPAD + ks * 288 + ((l >> 4) * 8)];
#pragma unroll
        for (int bch = 0; bch < 3; ++bch) {
            bf16x8 bf[3];
#pragma unroll
            for (int u = 0; u < 3; ++u) bf[u] = *(const bf16x8*)(srow + (bch * 3 + u) * 32);
#pragma unroll
            for (int u = 0; u < 3; ++u)
                oacc = __builtin_amdgcn_mfma_f32_16x16x32_bf16(oaf[bch * 3 + u], bf[u], oacc, 0, 0, 0);
        }
    }
    __syncthreads();                           // S(int) reads done
    float* red = (float*)S;                    // 8 waves x 64 lanes x f32x4 = 8KB
    *(f32x4*)&red[wv * 256 + l * 4] = oacc;
    __syncthreads();
    if (wv < 2) {
        f32x4 s0 = *(const f32x4*)&red[(0 * 2 + wv) * 256 + l * 4];
        f32x4 s1 = *(const f32x4*)&red[(1 * 2 + wv) * 256 + l * 4];
        f32x4 s2 = *(const f32x4*)&red[(2 * 2 + wv) * 256 + l * 4];
        f32x4 s3 = *(const f32x4*)&red[(3 * 2 + wv) * 256 + l * 4];
        f32x4 sm = (s0 + s1) + (s2 + s3);
#pragma unroll
        for (int r = 0; r < 4; ++r) {
            int oc = wv * 16 + ((l >> 4) << 2) + r;
            if (oc < 18) {
                offL[l & 15][oc] = sm[r] + obv[oc];
            } else if (oc < 27) {
                float z = sm[r] + obv[oc];
                maskL[l & 15][oc - 18] = 1.f / (1.f + expf(-z));
            }
        }
    }
    __syncthreads();                           // offL/maskL ready

    // ---- bilinear params: lane j (<18) computes set (pp=wv*2+j/9, k=j%9) ----
    int pw0i = 0, pw1i = 0, pw2i = 0, pw3i = 0, pa0 = 0, pa1 = 0, pdx = 0;
    if (l < 18) {
        const int p = wv * 2 + l / 9;
        const int k = l - 9 * (l / 9);
        const float offy = offL[p][2 * k];
        const float offx = offL[p][2 * k + 1];
        const float m    = maskL[p][k];
        const float py = (float)(hy + (k / 3 - 1) * dil) + offy;
        const float px = (float)(wx0 + p + (k % 3 - 1) * dil) + offx;
        const float y0f = floorf(py), x0f = floorf(px);
        const float ly = py - y0f, lx = px - x0f;
        const int y0 = (int)y0f, x0 = (int)x0f;
        const float yv0 = (y0 >= 0 && y0 < Hn)      ? 1.f : 0.f;
        const float yv1 = (y0 >= -1 && y0 < Hn - 1) ? 1.f : 0.f;
        const float xv0 = (x0 >= 0 && x0 < Wn)      ? 1.f : 0.f;
        const float xv1 = (x0 >= -1 && x0 < Wn - 1) ? 1.f : 0.f;
        const float wy0 = (1.f - ly) * yv0 * m;
        const float wy1 = ly * yv1 * m;
        const float wxa = (1.f - lx) * xv0;
        const float wxb = lx * xv1;
        pw0i = __float_as_int(wy0 * wxa);
        pw1i = __float_as_int(wy0 * wxb);
        pw2i = __float_as_int(wy1 * wxa);
        pw3i = __float_as_int(wy1 * wxb);
        const int y0c = min(max(y0, 0), Hn - 1), y1c = min(max(y0 + 1, 0), Hn - 1);
        const int x0c = min(max(x0, 0), Wn - 1), x1c = min(max(x0 + 1, 0), Wn - 1);
        pa0 = (basep + y0c * Wn + x0c) * 128;
        pa1 = (basep + y1c * Wn + x1c) * 128;
        pdx = (x1c - x0c) * 128;
    }

    // ---- prefetch first 6 dconv A-frags (consumed after next barrier) ----
    bf16x8 daf[6];
    {
        const short* darow = wbs + (wv * 36) * 512 + l * 8;
#pragma unroll
        for (int u = 0; u < 6; ++u) daf[u] = *(const bf16x8*)(darow + u * 512);
    }

    // ---- gather-bil: bf16 source (uint = 2ch), unpack->FMA->pack ----
#pragma unroll
    for (int bch = 0; bch < 6; ++bch) {
        unsigned u00[3], u01[3], u10[3], u11[3];
        float    w00[3], w01[3], w10[3], w11[3];
#pragma unroll
        for (int u = 0; u < 3; ++u) {
            const int i = bch * 3 + u;
            w00[u] = __int_as_float(__builtin_amdgcn_readlane(pw0i, i));
            w01[u] = __int_as_float(__builtin_amdgcn_readlane(pw1i, i));
            w10[u] = __int_as_float(__builtin_amdgcn_readlane(pw2i, i));
            w11[u] = __int_as_float(__builtin_amdgcn_readlane(pw3i, i));
            const int a00 = __builtin_amdgcn_readlane(pa0, i);
            const int a11 = __builtin_amdgcn_readlane(pa1, i);
            const int dxk = __builtin_amdgcn_readlane(pdx, i);
            const unsigned short* xp = xTb + a00;
            const unsigned short* xq = xTb + a11;
            u00[u] = ((const unsigned*)xp)[l];
            u01[u] = ((const unsigned*)(xp + dxk))[l];
            u10[u] = ((const unsigned*)(xq - dxk))[l];
            u11[u] = ((const unsigned*)xq)[l];
        }
#pragma unroll
        for (int u = 0; u < 3; ++u) {
            const int i  = bch * 3 + u;
            const int di = i / 9;
            const int k  = i - di * 9;
            const int pp = wv * 2 + di;
            const float f00a = __int_as_float(u00[u] << 16);
            const float f00b = __int_as_float(u00[u] & 0xffff0000u);
            const float f01a = __int_as_float(u01[u] << 16);
            const float f01b = __int_as_float(u01[u] & 0xffff0000u);
            const float f10a = __int_as_float(u10[u] << 16);
            const float f10b = __int_as_float(u10[u] & 0xffff0000u);
            const float f11a = __int_as_float(u11[u] << 16);
            const float f11b = __int_as_float(u11[u] & 0xffff0000u);
            float s0 = w00[u] * f00a + w01[u] * f01a + w10[u] * f10a + w11[u] * f11a;
            float s1 = w00[u] * f00b + w01[u] * f01b + w10[u] * f10b + w11[u] * f11b;
            ((unsigned*)&S[pp * KPAD + k * 128])[l] = pack2(s0, s1);
        }
    }
    __syncthreads();

    // ---- dconv GEMM: batch 0 A-frags from prefetched regs ----
    f32x4 dacc = {0.f, 0.f, 0.f, 0.f};
    {
        const short* darow = wbs + (wv * 36) * 512 + l * 8;
        const short* srow  = &S[(l & 15) * KPAD + ((l >> 4) * 8)];
        {   // batch 0 (u 0..5) from daf
            bf16x8 bf[6];
#pragma unroll
            for (int u = 0; u < 6; ++u) bf[u] = *(const bf16x8*)(srow + u * 32);
#pragma unroll
            for (int u = 0; u < 6; ++u)
                dacc = __builtin_amdgcn_mfma_f32_16x16x32_bf16(daf[u], bf[u], dacc, 0, 0, 0);
        }
#pragma unroll
        for (int bch = 1; bch < 6; ++bch) {
            bf16x8 af[6], bf[6];
#pragma unroll
            for (int u = 0; u < 6; ++u) af[u] = *(const bf16x8*)(darow + (bch * 6 + u) * 512);
#pragma unroll
            for (int u = 0; u < 6; ++u) bf[u] = *(const bf16x8*)(srow  + (bch * 6 + u) * 32);
#pragma unroll
            for (int u = 0; u < 6; ++u)
                dacc = __builtin_amdgcn_mfma_f32_16x16x32_bf16(af[u], bf[u], dacc, 0, 0, 0);
        }
    }

    // ---- epilogue: BN + ReLU + residual(f32) ----
    const int pp  = l & 15;
    const int ocb = wv * 16 + ((l >> 4) << 2);
    if (last) {
#pragma unroll
        for (int r = 0; r < 4; ++r) {
            const int oc = ocb + r;
            const float sc = gv[oc] * rsqrtf(vv[oc] + EPSn);
            float y = (dacc[r] - mv[oc]) * sc + bv[oc];
            y = fmaxf(y, 0.f);
            y += xTf[(pix0 + pp) * 128 + oc];
            outC[b * CHWn + oc * HWn + sp0 + pp] = y;
        }
    } else {
        __syncthreads();                       // all S reads done; alias O on S
        float* O = (float*)S;                  // O[16][132]
#pragma unroll
        for (int r = 0; r < 4; ++r) {
            const int oc = ocb + r;
            const float sc = gv[oc] * rsqrtf(vv[oc] + EPSn);
            float y = (dacc[r] - mv[oc]) * sc + bv[oc];
            O[pp * 132 + oc] = fmaxf(y, 0.f);
        }
        __syncthreads();
        const int o  = t * 4;                  // 0..2047
        const int qp = o >> 7, qc = o & 127;
        f32x4 yv = *(f32x4*)&O[qp * 132 + qc];
        f32x4 rv = *(const f32x4*)&xTf[(pix0 + qp) * 128 + qc];
        yv += rv;
        *(f32x4*)&outTf[(pix0 + qp) * 128 + qc] = yv;
        uint2 pk;
        pk.x = pack2(yv[0], yv[1]);
        pk.y = pack2(yv[2], yv[3]);
        *(uint2*)&outTb[(pix0 + qp) * 128 + qc] = pk;
    }
}

extern "C" void kernel_launch(void* const* d_in, const int* in_sizes, int n_in,
                              void* d_out, int out_size, void* d_ws, size_t ws_size,
                              hipStream_t stream) {
    (void)in_sizes; (void)n_in; (void)out_size; (void)ws_size;

    const float* hu = (const float*)d_in[0];

    short* wbs  = (short*)d_ws;                          // 3 * 147456 shorts
    short* owbs = wbs + 3 * Cn * KCn;                    // 3 * 36864 shorts
    unsigned short* T0b = (unsigned short*)(owbs + 3 * 32 * KCn);  // Bn*CHWn
    unsigned short* T1b = T0b + Bn * CHWn;
    float* T0f = (float*)(T1b + Bn * CHWn);
    float* T1f = T0f + Bn * CHWn;

    cvt_w_all<<<3 * 576, 256, 0, stream>>>(
        (const float*)d_in[3], (const float*)d_in[10], (const float*)d_in[17], wbs);
    cvt_ow_all<<<3 * 144, 256, 0, stream>>>(
        (const float*)d_in[1], (const float*)d_in[8], (const float*)d_in[15], owbs);

    nchw2nhwc<<<(Bn * HWn) / 64, 256, 0, stream>>>(hu, T0f, T0b);

    const int dils[3] = {2, 4, 8};
    const unsigned short* insb[3] = {T0b, T1b, T0b};
    const float*          insf[3] = {T0f, T1f, T0f};
    float*          outsf[3] = {T1f, T0f, nullptr};
    unsigned short* outsb[3] = {T1b, T0b, nullptr};
    const int nblk = (Bn * HWn) / 16;             // 1152

    for (int i = 0; i < 3; ++i) {
        const float* obv = (const float*)d_in[2 + 7 * i];
        const float* gv  = (const float*)d_in[4 + 7 * i];
        const float* bv  = (const float*)d_in[5 + 7 * i];
        const float* mv  = (const float*)d_in[6 + 7 * i];
        const float* vv  = (const float*)d_in[7 + 7 * i];
        const int last = (i == 2);

        fused_stage<<<nblk, 512, 0, stream>>>(
            insb[i], insf[i], wbs + i * Cn * KCn, owbs + i * 32 * KCn, obv,
            gv, bv, mv, vv, outsf[i], outsb[i],
            last ? (float*)d_out : nullptr, dils[i], last);
    }
}

// Round 19
// 106.303 us; speedup vs baseline: 1.3395x; 1.0731x over previous
//
#include <hip/hip_runtime.h>
#include <math.h>

constexpr int Bn  = 2;
constexpr int Cn  = 128;
constexpr int Hn  = 96;
constexpr int Wn  = 96;
constexpr int HWn = Hn * Wn;        // 9216
constexpr int CHWn = Cn * HWn;      // 1179648
constexpr int KCn = Cn * 9;         // 1152
constexpr float EPSn = 1e-5f;
constexpr int KPAD = 1160;          // LDS row stride in shorts (2320B)

typedef short bf16x8 __attribute__((ext_vector_type(8)));
typedef float f32x4  __attribute__((ext_vector_type(4)));

static __device__ inline short f2bf(float f) {
    union { float f; unsigned u; } v; v.f = f;
    unsigned r = v.u + 0x7fff + ((v.u >> 16) & 1);
    return (short)(r >> 16);
}
static __device__ inline unsigned pack2(float a, float b) {
    unsigned r;
    asm("v_cvt_pk_bf16_f32 %0, %1, %2" : "=v"(r) : "v"(a), "v"(b));
    return r;
}
static __device__ inline float bflo(unsigned u) { return __int_as_float(u << 16); }
static __device__ inline float bfhi(unsigned u) { return __int_as_float(u & 0xffff0000u); }

// Fragment-shuffled dconv weights, 3 stages in one launch (r14 mapping).
__global__ __launch_bounds__(256) void cvt_w_all(
    const float* __restrict__ w1, const float* __restrict__ w2,
    const float* __restrict__ w3, short* __restrict__ wbs)
{
    const int bid = blockIdx.x;               // 3*576
    const int stage = bid / 576;
    const float* w = (stage == 0) ? w1 : (stage == 1) ? w2 : w3;
    int t = (bid - stage * 576) * 256 + threadIdx.x;
    int e = t & 7, l = (t >> 3) & 63, rest = t >> 9;   // rest 0..287
    int j = rest % 36, g = rest / 36;
    int lr = l & 15, lq = l >> 4;
    int o = g * 16 + lr;
    int kidx = j * 32 + lq * 8 + e;
    int k = kidx >> 7, c = kidx & 127;
    wbs[stage * Cn * KCn + t] = f2bf(w[o * KCn + c * 9 + k]);
}

// Fragment-shuffled offconv weights, 3 stages (r14 mapping: wvv=(mh,ks)).
__global__ __launch_bounds__(256) void cvt_ow_all(
    const float* __restrict__ w1, const float* __restrict__ w2,
    const float* __restrict__ w3, short* __restrict__ owbs)
{
    const int bid = blockIdx.x;               // 3*144
    const int stage = bid / 144;
    const float* ow = (stage == 0) ? w1 : (stage == 1) ? w2 : w3;
    int t = (bid - stage * 144) * 256 + threadIdx.x;
    int e = t & 7, l = (t >> 3) & 63, rest = t >> 9;   // rest 0..71
    int kk = rest % 9, wvv = rest / 9;
    int mh = wvv & 1, ks = wvv >> 1;
    int lr = l & 15, lq = l >> 4;
    int o = mh * 16 + lr;
    int kidx = ks * 288 + kk * 32 + lq * 8 + e;
    int k = kidx >> 7, c = kidx & 127;
    owbs[stage * 32 * KCn + t] = (o < 27) ? f2bf(ow[o * KCn + c * 9 + k]) : (short)0;
}

// NCHW -> NHWC bf16 (single output; residual chain lives in bf16)
__global__ __launch_bounds__(256) void nchw2nhwc(
    const float* __restrict__ x, unsigned short* __restrict__ xTb)
{
    __shared__ float Tl[128][65];
    const int t = threadIdx.x;
    const int pix0 = blockIdx.x * 64;
    const int b   = pix0 / HWn;
    const int sp0 = pix0 - b * HWn;
    const float* xb = x + b * CHWn + sp0 + (t & 63);
    const int c0 = t >> 6;
#pragma unroll 8
    for (int i = 0; i < 32; ++i) {
        const int c = c0 + 4 * i;
        Tl[c][t & 63] = xb[c * HWn];
    }
    __syncthreads();
    unsigned short* dstb = xTb + pix0 * 128;
#pragma unroll 8
    for (int i = 0; i < 32; ++i) {
        const int o = t + 256 * i;
        dstb[o] = (unsigned short)f2bf(Tl[o & 127][o >> 7]);
    }
}

// One fused residual block, 16 pixels / 512 threads, NHWC bf16 everywhere,
// fragment-shuffled weights, cross-barrier A-frag + residual prefetch.
__global__ __launch_bounds__(512, 6) void fused_stage(
    const unsigned short* __restrict__ xTb,
    const short* __restrict__ wbs, const short* __restrict__ owbs,
    const float* __restrict__ obv,
    const float* __restrict__ gv, const float* __restrict__ bv,
    const float* __restrict__ mv, const float* __restrict__ vv,
    unsigned short* __restrict__ outTb,
    float* __restrict__ outC, int dil, int last)
{
    __shared__ short S[16 * KPAD];            // im2col tile S[p][K'], 37120B
    __shared__ float offL[16][18];
    __shared__ float maskL[16][9];

    const int t   = threadIdx.x;
    const int l   = t & 63;
    const int wv  = t >> 6;                   // wave 0..7
    const int lh  = l >> 5;                   // pixel half (gather-int)
    const int lc  = l & 31;                   // channel quad (gather-int)

    // XCD-aware bijective swizzle: 1152 blocks = 8 XCDs x 144 contiguous
    const int bid = blockIdx.x;
    const int swz = (bid & 7) * 144 + (bid >> 3);
    const int pix0 = swz * 16;
    const int b   = pix0 / HWn;
    const int sp0 = pix0 - b * HWn;
    const int hy  = sp0 / Wn;
    const int wx0 = sp0 - hy * Wn;
    const int basep = b * HWn;

    // ---- prefetch offconv A-frags (consumed after the barrier) ----
    bf16x8 oaf[9];
    {
        const short* oarow = owbs + (wv * 9) * 512 + l * 8;
#pragma unroll
        for (int u = 0; u < 9; ++u) oaf[u] = *(const bf16x8*)(oarow + u * 512);
    }

    // ---- gather-int: bf16 source, pure masked copy (uint2 = 4ch) ----
#pragma unroll
    for (int bch = 0; bch < 3; ++bch) {
        uint2 vle[3];
#pragma unroll
        for (int u = 0; u < 3; ++u) {
            const int k  = bch * 3 + u;
            const int pp = wv * 2 + lh;
            const int iy = hy + (k / 3 - 1) * dil;
            const int ix = wx0 + pp + (k % 3 - 1) * dil;
            const bool v = (iy >= 0) && (iy < Hn) && (ix >= 0) && (ix < Wn);
            const int aof = v ? (basep + iy * Wn + ix) : basep;
            uint2 val = ((const uint2*)(xTb + aof * 128))[lc];
            vle[u].x = v ? val.x : 0u;
            vle[u].y = v ? val.y : 0u;
        }
#pragma unroll
        for (int u = 0; u < 3; ++u) {
            const int k  = bch * 3 + u;
            const int pp = wv * 2 + lh;
            ((uint2*)&S[pp * KPAD + k * 128])[lc] = vle[u];
        }
    }
    __syncthreads();

    // ---- offconv GEMM: A from prefetched regs, B from S ----
    f32x4 oacc = {0.f, 0.f, 0.f, 0.f};
    {
        const int ks = wv >> 1;
        const short* srow = &S[(l & 15) * KPAD + ks * 288 + ((l >> 4) * 8)];
#pragma unroll
        for (int bch = 0; bch < 3; ++bch) {
            bf16x8 bf[3];
#pragma unroll
            for (int u = 0; u < 3; ++u) bf[u] = *(const bf16x8*)(srow + (bch * 3 + u) * 32);
#pragma unroll
            for (int u = 0; u < 3; ++u)
                oacc = __builtin_amdgcn_mfma_f32_16x16x32_bf16(oaf[bch * 3 + u], bf[u], oacc, 0, 0, 0);
        }
    }
    __syncthreads();                           // S(int) reads done
    float* red = (float*)S;                    // 8 waves x 64 lanes x f32x4 = 8KB
    *(f32x4*)&red[wv * 256 + l * 4] = oacc;
    __syncthreads();
    if (wv < 2) {
        f32x4 s0 = *(const f32x4*)&red[(0 * 2 + wv) * 256 + l * 4];
        f32x4 s1 = *(const f32x4*)&red[(1 * 2 + wv) * 256 + l * 4];
        f32x4 s2 = *(const f32x4*)&red[(2 * 2 + wv) * 256 + l * 4];
        f32x4 s3 = *(const f32x4*)&red[(3 * 2 + wv) * 256 + l * 4];
        f32x4 sm = (s0 + s1) + (s2 + s3);
#pragma unroll
        for (int r = 0; r < 4; ++r) {
            int oc = wv * 16 + ((l >> 4) << 2) + r;
            if (oc < 18) {
                offL[l & 15][oc] = sm[r] + obv[oc];
            } else if (oc < 27) {
                float z = sm[r] + obv[oc];
                maskL[l & 15][oc - 18] = 1.f / (1.f + expf(-z));
            }
        }
    }
    __syncthreads();                           // offL/maskL ready

    // ---- bilinear params: lane j (<18) computes set (pp=wv*2+j/9, k=j%9) ----
    int pw0i = 0, pw1i = 0, pw2i = 0, pw3i = 0, pa0 = 0, pa1 = 0, pdx = 0;
    if (l < 18) {
        const int p = wv * 2 + l / 9;
        const int k = l - 9 * (l / 9);
        const float offy = offL[p][2 * k];
        const float offx = offL[p][2 * k + 1];
        const float m    = maskL[p][k];
        const float py = (float)(hy + (k / 3 - 1) * dil) + offy;
        const float px = (float)(wx0 + p + (k % 3 - 1) * dil) + offx;
        const float y0f = floorf(py), x0f = floorf(px);
        const float ly = py - y0f, lx = px - x0f;
        const int y0 = (int)y0f, x0 = (int)x0f;
        const float yv0 = (y0 >= 0 && y0 < Hn)      ? 1.f : 0.f;
        const float yv1 = (y0 >= -1 && y0 < Hn - 1) ? 1.f : 0.f;
        const float xv0 = (x0 >= 0 && x0 < Wn)      ? 1.f : 0.f;
        const float xv1 = (x0 >= -1 && x0 < Wn - 1) ? 1.f : 0.f;
        const float wy0 = (1.f - ly) * yv0 * m;
        const float wy1 = ly * yv1 * m;
        const float wxa = (1.f - lx) * xv0;
        const float wxb = lx * xv1;
        pw0i = __float_as_int(wy0 * wxa);
        pw1i = __float_as_int(wy0 * wxb);
        pw2i = __float_as_int(wy1 * wxa);
        pw3i = __float_as_int(wy1 * wxb);
        const int y0c = min(max(y0, 0), Hn - 1), y1c = min(max(y0 + 1, 0), Hn - 1);
        const int x0c = min(max(x0, 0), Wn - 1), x1c = min(max(x0 + 1, 0), Wn - 1);
        pa0 = (basep + y0c * Wn + x0c) * 128;
        pa1 = (basep + y1c * Wn + x1c) * 128;
        pdx = (x1c - x0c) * 128;
    }

    // ---- prefetch first 6 dconv A-frags + epilogue residual ----
    bf16x8 daf[6];
    {
        const short* darow = wbs + (wv * 36) * 512 + l * 8;
#pragma unroll
        for (int u = 0; u < 6; ++u) daf[u] = *(const bf16x8*)(darow + u * 512);
    }
    const int pp  = l & 15;
    const int ocb = wv * 16 + ((l >> 4) << 2);
    uint2 resb;
    if (last) {
        resb = *(const uint2*)&xTb[(pix0 + pp) * 128 + ocb];
    } else {
        const int o = t * 4;
        resb = *(const uint2*)&xTb[(pix0 + (o >> 7)) * 128 + (o & 127)];
    }

    // ---- gather-bil: bf16 source (uint = 2ch), unpack->FMA->pack ----
#pragma unroll
    for (int bch = 0; bch < 6; ++bch) {
        unsigned u00[3], u01[3], u10[3], u11[3];
        float    w00[3], w01[3], w10[3], w11[3];
#pragma unroll
        for (int u = 0; u < 3; ++u) {
            const int i = bch * 3 + u;
            w00[u] = __int_as_float(__builtin_amdgcn_readlane(pw0i, i));
            w01[u] = __int_as_float(__builtin_amdgcn_readlane(pw1i, i));
            w10[u] = __int_as_float(__builtin_amdgcn_readlane(pw2i, i));
            w11[u] = __int_as_float(__builtin_amdgcn_readlane(pw3i, i));
            const int a00 = __builtin_amdgcn_readlane(pa0, i);
            const int a11 = __builtin_amdgcn_readlane(pa1, i);
            const int dxk = __builtin_amdgcn_readlane(pdx, i);
            const unsigned short* xp = xTb + a00;
            const unsigned short* xq = xTb + a11;
            u00[u] = ((const unsigned*)xp)[l];
            u01[u] = ((const unsigned*)(xp + dxk))[l];
            u10[u] = ((const unsigned*)(xq - dxk))[l];
            u11[u] = ((const unsigned*)xq)[l];
        }
#pragma unroll
        for (int u = 0; u < 3; ++u) {
            const int i  = bch * 3 + u;
            const int di = i / 9;
            const int k  = i - di * 9;
            const int ppw = wv * 2 + di;
            float s0 = w00[u] * bflo(u00[u]) + w01[u] * bflo(u01[u])
                     + w10[u] * bflo(u10[u]) + w11[u] * bflo(u11[u]);
            float s1 = w00[u] * bfhi(u00[u]) + w01[u] * bfhi(u01[u])
                     + w10[u] * bfhi(u10[u]) + w11[u] * bfhi(u11[u]);
            ((unsigned*)&S[ppw * KPAD + k * 128])[l] = pack2(s0, s1);
        }
    }
    __syncthreads();

    // ---- dconv GEMM: batch 0 A-frags from prefetched regs ----
    f32x4 dacc = {0.f, 0.f, 0.f, 0.f};
    {
        const short* darow = wbs + (wv * 36) * 512 + l * 8;
        const short* srow  = &S[(l & 15) * KPAD + ((l >> 4) * 8)];
        {   // batch 0 (u 0..5) from daf
            bf16x8 bf[6];
#pragma unroll
            for (int u = 0; u < 6; ++u) bf[u] = *(const bf16x8*)(srow + u * 32);
#pragma unroll
            for (int u = 0; u < 6; ++u)
                dacc = __builtin_amdgcn_mfma_f32_16x16x32_bf16(daf[u], bf[u], dacc, 0, 0, 0);
        }
#pragma unroll
        for (int bch = 1; bch < 6; ++bch) {
            bf16x8 af[6], bf[6];
#pragma unroll
            for (int u = 0; u < 6; ++u) af[u] = *(const bf16x8*)(darow + (bch * 6 + u) * 512);
#pragma unroll
            for (int u = 0; u < 6; ++u) bf[u] = *(const bf16x8*)(srow  + (bch * 6 + u) * 32);
#pragma unroll
            for (int u = 0; u < 6; ++u)
                dacc = __builtin_amdgcn_mfma_f32_16x16x32_bf16(af[u], bf[u], dacc, 0, 0, 0);
        }
    }

    // ---- epilogue: BN + ReLU + residual(bf16) ----
    if (last) {
        const float rs[4] = {bflo(resb.x), bfhi(resb.x), bflo(resb.y), bfhi(resb.y)};
#pragma unroll
        for (int r = 0; r < 4; ++r) {
            const int oc = ocb + r;
            const float sc = gv[oc] * rsqrtf(vv[oc] + EPSn);
            float y = (dacc[r] - mv[oc]) * sc + bv[oc];
            y = fmaxf(y, 0.f) + rs[r];
            outC[b * CHWn + oc * HWn + sp0 + pp] = y;
        }
    } else {
        __syncthreads();                       // all S reads done; alias O on S
        float* O = (float*)S;                  // O[16][132]
#pragma unroll
        for (int r = 0; r < 4; ++r) {
            const int oc = ocb + r;
            const float sc = gv[oc] * rsqrtf(vv[oc] + EPSn);
            float y = (dacc[r] - mv[oc]) * sc + bv[oc];
            O[pp * 132 + oc] = fmaxf(y, 0.f);
        }
        __syncthreads();
        const int o  = t * 4;                  // 0..2047
        const int qp = o >> 7, qc = o & 127;
        f32x4 yv = *(f32x4*)&O[qp * 132 + qc];
        yv[0] += bflo(resb.x);
        yv[1] += bfhi(resb.x);
        yv[2] += bflo(resb.y);
        yv[3] += bfhi(resb.y);
        uint2 pk;
        pk.x = pack2(yv[0], yv[1]);
        pk.y = pack2(yv[2], yv[3]);
        *(uint2*)&outTb[(pix0 + qp) * 128 + qc] = pk;
    }
}

extern "C" void kernel_launch(void* const* d_in, const int* in_sizes, int n_in,
                              void* d_out, int out_size, void* d_ws, size_t ws_size,
                              hipStream_t stream) {
    (void)in_sizes; (void)n_in; (void)out_size; (void)ws_size;

    const float* hu = (const float*)d_in[0];

    short* wbs  = (short*)d_ws;                          // 3 * 147456 shorts
    short* owbs = wbs + 3 * Cn * KCn;                    // 3 * 36864 shorts
    unsigned short* T0b = (unsigned short*)(owbs + 3 * 32 * KCn);  // Bn*CHWn
    unsigned short* T1b = T0b + Bn * CHWn;

    cvt_w_all<<<3 * 576, 256, 0, stream>>>(
        (const float*)d_in[3], (const float*)d_in[10], (const float*)d_in[17], wbs);
    cvt_ow_all<<<3 * 144, 256, 0, stream>>>(
        (const float*)d_in[1], (const float*)d_in[8], (const float*)d_in[15], owbs);

    nchw2nhwc<<<(Bn * HWn) / 64, 256, 0, stream>>>(hu, T0b);

    const int dils[3] = {2, 4, 8};
    const unsigned short* insb[3] = {T0b, T1b, T0b};
    unsigned short* outsb[3] = {T1b, T0b, nullptr};
    const int nblk = (Bn * HWn) / 16;             // 1152

    for (int i = 0; i < 3; ++i) {
        const float* obv = (const float*)d_in[2 + 7 * i];
        const float* gv  = (const float*)d_in[4 + 7 * i];
        const float* bv  = (const float*)d_in[5 + 7 * i];
        const float* mv  = (const float*)d_in[6 + 7 * i];
        const float* vv  = (const float*)d_in[7 + 7 * i];
        const int last = (i == 2);

        fused_stage<<<nblk, 512, 0, stream>>>(
            insb[i], wbs + i * Cn * KCn, owbs + i * 32 * KCn, obv,
            gv, bv, mv, vv, outsb[i],
            last ? (float*)d_out : nullptr, dils[i], last);
    }
}

// Round 20
// 100.678 us; speedup vs baseline: 1.4143x; 1.0559x over previous
//
#include <hip/hip_runtime.h>
#include <math.h>

constexpr int Bn  = 2;
constexpr int Cn  = 128;
constexpr int Hn  = 96;
constexpr int Wn  = 96;
constexpr int HWn = Hn * Wn;        // 9216
constexpr int CHWn = Cn * HWn;      // 1179648
constexpr int KCn = Cn * 9;         // 1152
constexpr float EPSn = 1e-5f;
constexpr int KPAD = 1160;          // LDS row stride in shorts (2320B)

typedef short bf16x8 __attribute__((ext_vector_type(8)));
typedef float f32x4  __attribute__((ext_vector_type(4)));

static __device__ inline short f2bf(float f) {
    union { float f; unsigned u; } v; v.f = f;
    unsigned r = v.u + 0x7fff + ((v.u >> 16) & 1);
    return (short)(r >> 16);
}
static __device__ inline unsigned pack2(float a, float b) {
    unsigned r;
    asm("v_cvt_pk_bf16_f32 %0, %1, %2" : "=v"(r) : "v"(a), "v"(b));
    return r;
}
static __device__ inline float bflo(unsigned u) { return __int_as_float(u << 16); }
static __device__ inline float bfhi(unsigned u) { return __int_as_float(u & 0xffff0000u); }

// Merged prep: blocks [0,1728) cvt_w (3 stages), [1728,2160) cvt_ow (3 stages),
// [2160,2448) NCHW->NHWC bf16 transpose.
__global__ __launch_bounds__(256) void prep_all(
    const float* __restrict__ hu,
    const float* __restrict__ w1, const float* __restrict__ w2,
    const float* __restrict__ w3,
    const float* __restrict__ o1, const float* __restrict__ o2,
    const float* __restrict__ o3,
    short* __restrict__ wbs, short* __restrict__ owbs,
    unsigned short* __restrict__ xTb)
{
    __shared__ float Tl[128][65];
    const int bid = blockIdx.x;
    if (bid < 1728) {
        const int stage = bid / 576;
        const float* w = (stage == 0) ? w1 : (stage == 1) ? w2 : w3;
        int t = (bid - stage * 576) * 256 + threadIdx.x;
        int e = t & 7, l = (t >> 3) & 63, rest = t >> 9;   // rest 0..287
        int j = rest % 36, g = rest / 36;
        int lr = l & 15, lq = l >> 4;
        int o = g * 16 + lr;
        int kidx = j * 32 + lq * 8 + e;
        int k = kidx >> 7, c = kidx & 127;
        wbs[stage * Cn * KCn + t] = f2bf(w[o * KCn + c * 9 + k]);
    } else if (bid < 2160) {
        const int rb = bid - 1728;
        const int stage = rb / 144;
        const float* ow = (stage == 0) ? o1 : (stage == 1) ? o2 : o3;
        int t = (rb - stage * 144) * 256 + threadIdx.x;
        int e = t & 7, l = (t >> 3) & 63, rest = t >> 9;   // rest 0..71
        int kk = rest % 9, wvv = rest / 9;
        int mh = wvv & 1, ks = wvv >> 1;
        int lr = l & 15, lq = l >> 4;
        int o = mh * 16 + lr;
        int kidx = ks * 288 + kk * 32 + lq * 8 + e;
        int k = kidx >> 7, c = kidx & 127;
        owbs[stage * 32 * KCn + t] = (o < 27) ? f2bf(ow[o * KCn + c * 9 + k]) : (short)0;
    } else {
        const int t = threadIdx.x;
        const int pix0 = (bid - 2160) * 64;
        const int b   = pix0 / HWn;
        const int sp0 = pix0 - b * HWn;
        const float* xb = hu + b * CHWn + sp0 + (t & 63);
        const int c0 = t >> 6;
#pragma unroll 8
        for (int i = 0; i < 32; ++i) {
            const int c = c0 + 4 * i;
            Tl[c][t & 63] = xb[c * HWn];
        }
        __syncthreads();
        unsigned short* dstb = xTb + pix0 * 128;
#pragma unroll 8
        for (int i = 0; i < 32; ++i) {
            const int o = t + 256 * i;
            dstb[o] = (unsigned short)f2bf(Tl[o & 127][o >> 7]);
        }
    }
}

// One fused residual block, 16 pixels / 512 threads, NHWC bf16 everywhere,
// fragment-shuffled weights, trimmed cross-barrier prefetch, 4 blocks/CU.
__global__ __launch_bounds__(512, 8) void fused_stage(
    const unsigned short* __restrict__ xTb,
    const short* __restrict__ wbs, const short* __restrict__ owbs,
    const float* __restrict__ obv,
    const float* __restrict__ gv, const float* __restrict__ bv,
    const float* __restrict__ mv, const float* __restrict__ vv,
    unsigned short* __restrict__ outTb,
    float* __restrict__ outC, int dil, int last)
{
    __shared__ short S[16 * KPAD];            // im2col tile S[p][K'], 37120B
    __shared__ float offL[16][18];
    __shared__ float maskL[16][9];

    const int t   = threadIdx.x;
    const int l   = t & 63;
    const int wv  = t >> 6;                   // wave 0..7
    const int lh  = l >> 5;                   // pixel half (gather-int)
    const int lc  = l & 31;                   // channel quad (gather-int)

    // XCD-aware bijective swizzle: 1152 blocks = 8 XCDs x 144 contiguous
    const int bid = blockIdx.x;
    const int swz = (bid & 7) * 144 + (bid >> 3);
    const int pix0 = swz * 16;
    const int b   = pix0 / HWn;
    const int sp0 = pix0 - b * HWn;
    const int hy  = sp0 / Wn;
    const int wx0 = sp0 - hy * Wn;
    const int basep = b * HWn;

    // ---- prefetch first 6 offconv A-frags (consumed after the barrier) ----
    bf16x8 oaf[6];
    {
        const short* oarow = owbs + (wv * 9) * 512 + l * 8;
#pragma unroll
        for (int u = 0; u < 6; ++u) oaf[u] = *(const bf16x8*)(oarow + u * 512);
    }

    // ---- gather-int: bf16 source, pure masked copy (uint2 = 4ch) ----
#pragma unroll
    for (int bch = 0; bch < 3; ++bch) {
        uint2 vle[3];
#pragma unroll
        for (int u = 0; u < 3; ++u) {
            const int k  = bch * 3 + u;
            const int pp = wv * 2 + lh;
            const int iy = hy + (k / 3 - 1) * dil;
            const int ix = wx0 + pp + (k % 3 - 1) * dil;
            const bool v = (iy >= 0) && (iy < Hn) && (ix >= 0) && (ix < Wn);
            const int aof = v ? (basep + iy * Wn + ix) : basep;
            uint2 val = ((const uint2*)(xTb + aof * 128))[lc];
            vle[u].x = v ? val.x : 0u;
            vle[u].y = v ? val.y : 0u;
        }
#pragma unroll
        for (int u = 0; u < 3; ++u) {
            const int k  = bch * 3 + u;
            const int pp = wv * 2 + lh;
            ((uint2*)&S[pp * KPAD + k * 128])[lc] = vle[u];
        }
    }
    __syncthreads();

    // ---- offconv GEMM: batches 0,1 from prefetched regs, batch 2 loads ----
    f32x4 oacc = {0.f, 0.f, 0.f, 0.f};
    {
        const int ks = wv >> 1;
        const short* oarow = owbs + (wv * 9) * 512 + l * 8;
        const short* srow  = &S[(l & 15) * KPAD + ks * 288 + ((l >> 4) * 8)];
#pragma unroll
        for (int bch = 0; bch < 2; ++bch) {
            bf16x8 bf[3];
#pragma unroll
            for (int u = 0; u < 3; ++u) bf[u] = *(const bf16x8*)(srow + (bch * 3 + u) * 32);
#pragma unroll
            for (int u = 0; u < 3; ++u)
                oacc = __builtin_amdgcn_mfma_f32_16x16x32_bf16(oaf[bch * 3 + u], bf[u], oacc, 0, 0, 0);
        }
        {
            bf16x8 af[3], bf[3];
#pragma unroll
            for (int u = 0; u < 3; ++u) af[u] = *(const bf16x8*)(oarow + (6 + u) * 512);
#pragma unroll
            for (int u = 0; u < 3; ++u) bf[u] = *(const bf16x8*)(srow + (6 + u) * 32);
#pragma unroll
            for (int u = 0; u < 3; ++u)
                oacc = __builtin_amdgcn_mfma_f32_16x16x32_bf16(af[u], bf[u], oacc, 0, 0, 0);
        }
    }
    __syncthreads();                           // S(int) reads done
    float* red = (float*)S;                    // 8 waves x 64 lanes x f32x4 = 8KB
    *(f32x4*)&red[wv * 256 + l * 4] = oacc;
    __syncthreads();
    if (wv < 2) {
        f32x4 s0 = *(const f32x4*)&red[(0 * 2 + wv) * 256 + l * 4];
        f32x4 s1 = *(const f32x4*)&red[(1 * 2 + wv) * 256 + l * 4];
        f32x4 s2 = *(const f32x4*)&red[(2 * 2 + wv) * 256 + l * 4];
        f32x4 s3 = *(const f32x4*)&red[(3 * 2 + wv) * 256 + l * 4];
        f32x4 sm = (s0 + s1) + (s2 + s3);
#pragma unroll
        for (int r = 0; r < 4; ++r) {
            int oc = wv * 16 + ((l >> 4) << 2) + r;
            if (oc < 18) {
                offL[l & 15][oc] = sm[r] + obv[oc];
            } else if (oc < 27) {
                float z = sm[r] + obv[oc];
                maskL[l & 15][oc - 18] = 1.f / (1.f + expf(-z));
            }
        }
    }
    __syncthreads();                           // offL/maskL ready

    // ---- bilinear params: lane j (<18) computes set (pp=wv*2+j/9, k=j%9) ----
    int pw0i = 0, pw1i = 0, pw2i = 0, pw3i = 0, pa0 = 0, pa1 = 0, pdx = 0;
    if (l < 18) {
        const int p = wv * 2 + l / 9;
        const int k = l - 9 * (l / 9);
        const float offy = offL[p][2 * k];
        const float offx = offL[p][2 * k + 1];
        const float m    = maskL[p][k];
        const float py = (float)(hy + (k / 3 - 1) * dil) + offy;
        const float px = (float)(wx0 + p + (k % 3 - 1) * dil) + offx;
        const float y0f = floorf(py), x0f = floorf(px);
        const float ly = py - y0f, lx = px - x0f;
        const int y0 = (int)y0f, x0 = (int)x0f;
        const float yv0 = (y0 >= 0 && y0 < Hn)      ? 1.f : 0.f;
        const float yv1 = (y0 >= -1 && y0 < Hn - 1) ? 1.f : 0.f;
        const float xv0 = (x0 >= 0 && x0 < Wn)      ? 1.f : 0.f;
        const float xv1 = (x0 >= -1 && x0 < Wn - 1) ? 1.f : 0.f;
        const float wy0 = (1.f - ly) * yv0 * m;
        const float wy1 = ly * yv1 * m;
        const float wxa = (1.f - lx) * xv0;
        const float wxb = lx * xv1;
        pw0i = __float_as_int(wy0 * wxa);
        pw1i = __float_as_int(wy0 * wxb);
        pw2i = __float_as_int(wy1 * wxa);
        pw3i = __float_as_int(wy1 * wxb);
        const int y0c = min(max(y0, 0), Hn - 1), y1c = min(max(y0 + 1, 0), Hn - 1);
        const int x0c = min(max(x0, 0), Wn - 1), x1c = min(max(x0 + 1, 0), Wn - 1);
        pa0 = (basep + y0c * Wn + x0c) * 128;
        pa1 = (basep + y1c * Wn + x1c) * 128;
        pdx = (x1c - x0c) * 128;
    }

    // ---- prefetch first 4 dconv A-frags + epilogue residual ----
    bf16x8 daf[4];
    {
        const short* darow = wbs + (wv * 36) * 512 + l * 8;
#pragma unroll
        for (int u = 0; u < 4; ++u) daf[u] = *(const bf16x8*)(darow + u * 512);
    }
    const int pp  = l & 15;
    const int ocb = wv * 16 + ((l >> 4) << 2);
    uint2 resb;
    if (last) {
        resb = *(const uint2*)&xTb[(pix0 + pp) * 128 + ocb];
    } else {
        const int o = t * 4;
        resb = *(const uint2*)&xTb[(pix0 + (o >> 7)) * 128 + (o & 127)];
    }

    // ---- gather-bil: bf16 source (uint = 2ch), unpack->FMA->pack ----
#pragma unroll
    for (int bch = 0; bch < 6; ++bch) {
        unsigned u00[3], u01[3], u10[3], u11[3];
        float    w00[3], w01[3], w10[3], w11[3];
#pragma unroll
        for (int u = 0; u < 3; ++u) {
            const int i = bch * 3 + u;
            w00[u] = __int_as_float(__builtin_amdgcn_readlane(pw0i, i));
            w01[u] = __int_as_float(__builtin_amdgcn_readlane(pw1i, i));
            w10[u] = __int_as_float(__builtin_amdgcn_readlane(pw2i, i));
            w11[u] = __int_as_float(__builtin_amdgcn_readlane(pw3i, i));
            const int a00 = __builtin_amdgcn_readlane(pa0, i);
            const int a11 = __builtin_amdgcn_readlane(pa1, i);
            const int dxk = __builtin_amdgcn_readlane(pdx, i);
            const unsigned short* xp = xTb + a00;
            const unsigned short* xq = xTb + a11;
            u00[u] = ((const unsigned*)xp)[l];
            u01[u] = ((const unsigned*)(xp + dxk))[l];
            u10[u] = ((const unsigned*)(xq - dxk))[l];
            u11[u] = ((const unsigned*)xq)[l];
        }
#pragma unroll
        for (int u = 0; u < 3; ++u) {
            const int i  = bch * 3 + u;
            const int di = i / 9;
            const int k  = i - di * 9;
            const int ppw = wv * 2 + di;
            float s0 = w00[u] * bflo(u00[u]) + w01[u] * bflo(u01[u])
                     + w10[u] * bflo(u10[u]) + w11[u] * bflo(u11[u]);
            float s1 = w00[u] * bfhi(u00[u]) + w01[u] * bfhi(u01[u])
                     + w10[u] * bfhi(u10[u]) + w11[u] * bfhi(u11[u]);
            ((unsigned*)&S[ppw * KPAD + k * 128])[l] = pack2(s0, s1);
        }
    }
    __syncthreads();

    // ---- dconv GEMM: batch 0 partly from prefetched regs ----
    f32x4 dacc = {0.f, 0.f, 0.f, 0.f};
    {
        const short* darow = wbs + (wv * 36) * 512 + l * 8;
        const short* srow  = &S[(l & 15) * KPAD + ((l >> 4) * 8)];
        {   // batch 0: u0..3 from daf, u4..5 from global
            bf16x8 af45[2], bf[6];
            af45[0] = *(const bf16x8*)(darow + 4 * 512);
            af45[1] = *(const bf16x8*)(darow + 5 * 512);
#pragma unroll
            for (int u = 0; u < 6; ++u) bf[u] = *(const bf16x8*)(srow + u * 32);
#pragma unroll
            for (int u = 0; u < 4; ++u)
                dacc = __builtin_amdgcn_mfma_f32_16x16x32_bf16(daf[u], bf[u], dacc, 0, 0, 0);
            dacc = __builtin_amdgcn_mfma_f32_16x16x32_bf16(af45[0], bf[4], dacc, 0, 0, 0);
            dacc = __builtin_amdgcn_mfma_f32_16x16x32_bf16(af45[1], bf[5], dacc, 0, 0, 0);
        }
#pragma unroll
        for (int bch = 1; bch < 6; ++bch) {
            bf16x8 af[6], bf[6];
#pragma unroll
            for (int u = 0; u < 6; ++u) af[u] = *(const bf16x8*)(darow + (bch * 6 + u) * 512);
#pragma unroll
            for (int u = 0; u < 6; ++u) bf[u] = *(const bf16x8*)(srow  + (bch * 6 + u) * 32);
#pragma unroll
            for (int u = 0; u < 6; ++u)
                dacc = __builtin_amdgcn_mfma_f32_16x16x32_bf16(af[u], bf[u], dacc, 0, 0, 0);
        }
    }

    // ---- epilogue: BN + ReLU + residual(bf16) ----
    if (last) {
        const float rs[4] = {bflo(resb.x), bfhi(resb.x), bflo(resb.y), bfhi(resb.y)};
#pragma unroll
        for (int r = 0; r < 4; ++r) {
            const int oc = ocb + r;
            const float sc = gv[oc] * rsqrtf(vv[oc] + EPSn);
            float y = (dacc[r] - mv[oc]) * sc + bv[oc];
            y = fmaxf(y, 0.f) + rs[r];
            outC[b * CHWn + oc * HWn + sp0 + pp] = y;
        }
    } else {
        __syncthreads();                       // all S reads done; alias O on S
        float* O = (float*)S;                  // O[16][132]
#pragma unroll
        for (int r = 0; r < 4; ++r) {
            const int oc = ocb + r;
            const float sc = gv[oc] * rsqrtf(vv[oc] + EPSn);
            float y = (dacc[r] - mv[oc]) * sc + bv[oc];
            O[pp * 132 + oc] = fmaxf(y, 0.f);
        }
        __syncthreads();
        const int o  = t * 4;                  // 0..2047
        const int qp = o >> 7, qc = o & 127;
        f32x4 yv = *(f32x4*)&O[qp * 132 + qc];
        yv[0] += bflo(resb.x);
        yv[1] += bfhi(resb.x);
        yv[2] += bflo(resb.y);
        yv[3] += bfhi(resb.y);
        uint2 pk;
        pk.x = pack2(yv[0], yv[1]);
        pk.y = pack2(yv[2], yv[3]);
        *(uint2*)&outTb[(pix0 + qp) * 128 + qc] = pk;
    }
}

extern "C" void kernel_launch(void* const* d_in, const int* in_sizes, int n_in,
                              void* d_out, int out_size, void* d_ws, size_t ws_size,
                              hipStream_t stream) {
    (void)in_sizes; (void)n_in; (void)out_size; (void)ws_size;

    const float* hu = (const float*)d_in[0];

    short* wbs  = (short*)d_ws;                          // 3 * 147456 shorts
    short* owbs = wbs + 3 * Cn * KCn;                    // 3 * 36864 shorts
    unsigned short* T0b = (unsigned short*)(owbs + 3 * 32 * KCn);  // Bn*CHWn
    unsigned short* T1b = T0b + Bn * CHWn;

    prep_all<<<2448, 256, 0, stream>>>(
        hu,
        (const float*)d_in[3], (const float*)d_in[10], (const float*)d_in[17],
        (const float*)d_in[1], (const float*)d_in[8], (const float*)d_in[15],
        wbs, owbs, T0b);

    const int dils[3] = {2, 4, 8};
    const unsigned short* insb[3] = {T0b, T1b, T0b};
    unsigned short* outsb[3] = {T1b, T0b, nullptr};
    const int nblk = (Bn * HWn) / 16;             // 1152

    for (int i = 0; i < 3; ++i) {
        const float* obv = (const float*)d_in[2 + 7 * i];
        const float* gv  = (const float*)d_in[4 + 7 * i];
        const float* bv  = (const float*)d_in[5 + 7 * i];
        const float* mv  = (const float*)d_in[6 + 7 * i];
        const float* vv  = (const float*)d_in[7 + 7 * i];
        const int last = (i == 2);

        fused_stage<<<nblk, 512, 0, stream>>>(
            insb[i], wbs + i * Cn * KCn, owbs + i * 32 * KCn, obv,
            gv, bv, mv, vv, outsb[i],
            last ? (float*)d_out : nullptr, dils[i], last);
    }
}

// Round 21
// 98.642 us; speedup vs baseline: 1.4435x; 1.0206x over previous
//
#include <hip/hip_runtime.h>
#include <math.h>

constexpr int Bn  = 2;
constexpr int Cn  = 128;
constexpr int Hn  = 96;
constexpr int Wn  = 96;
constexpr int HWn = Hn * Wn;        // 9216
constexpr int CHWn = Cn * HWn;      // 1179648
constexpr int KCn = Cn * 9;         // 1152
constexpr float EPSn = 1e-5f;
constexpr int KPAD = 1160;          // LDS row stride in shorts (2320B)

typedef short bf16x8 __attribute__((ext_vector_type(8)));
typedef float f32x4  __attribute__((ext_vector_type(4)));

static __device__ inline short f2bf(float f) {
    union { float f; unsigned u; } v; v.f = f;
    unsigned r = v.u + 0x7fff + ((v.u >> 16) & 1);
    return (short)(r >> 16);
}
static __device__ inline unsigned pack2(float a, float b) {
    unsigned r;
    asm("v_cvt_pk_bf16_f32 %0, %1, %2" : "=v"(r) : "v"(a), "v"(b));
    return r;
}
static __device__ inline float bflo(unsigned u) { return __int_as_float(u << 16); }
static __device__ inline float bfhi(unsigned u) { return __int_as_float(u & 0xffff0000u); }

// dconv weight fragment-shuffle mapping (pure function of flat index t)
static __device__ inline void shuf_w(int t, const float* __restrict__ w,
                                     short* __restrict__ dst)
{
    int e = t & 7, l = (t >> 3) & 63, rest = t >> 9;   // rest 0..287
    int j = rest % 36, g = rest / 36;
    int lr = l & 15, lq = l >> 4;
    int o = g * 16 + lr;
    int kidx = j * 32 + lq * 8 + e;
    int k = kidx >> 7, c = kidx & 127;
    dst[t] = f2bf(w[o * KCn + c * 9 + k]);
}
// offconv weight fragment-shuffle mapping
static __device__ inline void shuf_ow(int t, const float* __restrict__ ow,
                                      short* __restrict__ dst)
{
    int e = t & 7, l = (t >> 3) & 63, rest = t >> 9;   // rest 0..71
    int kk = rest % 9, wvv = rest / 9;
    int mh = wvv & 1, ks = wvv >> 1;
    int lr = l & 15, lq = l >> 4;
    int o = mh * 16 + lr;
    int kidx = ks * 288 + kk * 32 + lq * 8 + e;
    int k = kidx >> 7, c = kidx & 127;
    dst[t] = (o < 27) ? f2bf(ow[o * KCn + c * 9 + k]) : (short)0;
}

// prep: [0,576) w1 shuffle, [576,720) ow1 shuffle, [720,1008) NCHW->NHWC bf16
__global__ __launch_bounds__(256) void prep_s1(
    const float* __restrict__ hu,
    const float* __restrict__ w1, const float* __restrict__ o1,
    short* __restrict__ wbs, short* __restrict__ owbs,
    unsigned short* __restrict__ xTb)
{
    __shared__ float Tl[128][65];
    const int bid = blockIdx.x;
    if (bid < 576) {
        shuf_w(bid * 256 + threadIdx.x, w1, wbs);
    } else if (bid < 720) {
        shuf_ow((bid - 576) * 256 + threadIdx.x, o1, owbs);
    } else {
        const int t = threadIdx.x;
        const int pix0 = (bid - 720) * 64;
        const int b   = pix0 / HWn;
        const int sp0 = pix0 - b * HWn;
        const float* xb = hu + b * CHWn + sp0 + (t & 63);
        const int c0 = t >> 6;
#pragma unroll 8
        for (int i = 0; i < 32; ++i) {
            const int c = c0 + 4 * i;
            Tl[c][t & 63] = xb[c * HWn];
        }
        __syncthreads();
        unsigned short* dstb = xTb + pix0 * 128;
#pragma unroll 8
        for (int i = 0; i < 32; ++i) {
            const int o = t + 256 * i;
            dstb[o] = (unsigned short)f2bf(Tl[o & 127][o >> 7]);
        }
    }
}

// One fused residual block, 16 pixels / 512 threads, NHWC bf16 everywhere.
// Blocks [1152, 1152+360): shuffle NEXT stage's weights (tail-filling).
__global__ __launch_bounds__(512, 8) void fused_stage(
    const unsigned short* __restrict__ xTb,
    const short* __restrict__ wbs, const short* __restrict__ owbs,
    const float* __restrict__ obv,
    const float* __restrict__ gv, const float* __restrict__ bv,
    const float* __restrict__ mv, const float* __restrict__ vv,
    unsigned short* __restrict__ outTb,
    float* __restrict__ outC, int dil, int last,
    const float* __restrict__ wnext, const float* __restrict__ ownext,
    short* __restrict__ wbs_next, short* __restrict__ owbs_next)
{
    __shared__ short S[16 * KPAD];            // im2col tile S[p][K'], 37120B
    __shared__ float offL[16][18];
    __shared__ float maskL[16][9];

    const int bid = blockIdx.x;
    if (bid >= 1152) {                         // next-stage weight shuffle
        const int rb = bid - 1152;
        if (rb < 288) {
            shuf_w(rb * 512 + threadIdx.x, wnext, wbs_next);
        } else {
            shuf_ow((rb - 288) * 512 + threadIdx.x, ownext, owbs_next);
        }
        return;
    }

    const int t   = threadIdx.x;
    const int l   = t & 63;
    const int wv  = t >> 6;                   // wave 0..7
    const int lh  = l >> 5;                   // pixel half (gather-int)
    const int lc  = l & 31;                   // channel quad (gather-int)

    // XCD-aware bijective swizzle: 1152 main blocks = 8 XCDs x 144 contiguous
    const int swz = (bid & 7) * 144 + (bid >> 3);
    const int pix0 = swz * 16;
    const int b   = pix0 / HWn;
    const int sp0 = pix0 - b * HWn;
    const int hy  = sp0 / Wn;
    const int wx0 = sp0 - hy * Wn;
    const int basep = b * HWn;

    // ---- prefetch first 6 offconv A-frags (consumed after the barrier) ----
    bf16x8 oaf[6];
    {
        const short* oarow = owbs + (wv * 9) * 512 + l * 8;
#pragma unroll
        for (int u = 0; u < 6; ++u) oaf[u] = *(const bf16x8*)(oarow + u * 512);
    }

    // ---- gather-int: bf16 source, pure masked copy (uint2 = 4ch) ----
#pragma unroll
    for (int bch = 0; bch < 3; ++bch) {
        uint2 vle[3];
#pragma unroll
        for (int u = 0; u < 3; ++u) {
            const int k  = bch * 3 + u;
            const int pp = wv * 2 + lh;
            const int iy = hy + (k / 3 - 1) * dil;
            const int ix = wx0 + pp + (k % 3 - 1) * dil;
            const bool v = (iy >= 0) && (iy < Hn) && (ix >= 0) && (ix < Wn);
            const int aof = v ? (basep + iy * Wn + ix) : basep;
            uint2 val = ((const uint2*)(xTb + aof * 128))[lc];
            vle[u].x = v ? val.x : 0u;
            vle[u].y = v ? val.y : 0u;
        }
#pragma unroll
        for (int u = 0; u < 3; ++u) {
            const int k  = bch * 3 + u;
            const int pp = wv * 2 + lh;
            ((uint2*)&S[pp * KPAD + k * 128])[lc] = vle[u];
        }
    }
    __syncthreads();

    // ---- offconv GEMM: batches 0,1 from prefetched regs, batch 2 loads ----
    f32x4 oacc = {0.f, 0.f, 0.f, 0.f};
    {
        const int ks = wv >> 1;
        const short* oarow = owbs + (wv * 9) * 512 + l * 8;
        const short* srow  = &S[(l & 15) * KPAD + ks * 288 + ((l >> 4) * 8)];
#pragma unroll
        for (int bch = 0; bch < 2; ++bch) {
            bf16x8 bf[3];
#pragma unroll
            for (int u = 0; u < 3; ++u) bf[u] = *(const bf16x8*)(srow + (bch * 3 + u) * 32);
#pragma unroll
            for (int u = 0; u < 3; ++u)
                oacc = __builtin_amdgcn_mfma_f32_16x16x32_bf16(oaf[bch * 3 + u], bf[u], oacc, 0, 0, 0);
        }
        {
            bf16x8 af[3], bf[3];
#pragma unroll
            for (int u = 0; u < 3; ++u) af[u] = *(const bf16x8*)(oarow + (6 + u) * 512);
#pragma unroll
            for (int u = 0; u < 3; ++u) bf[u] = *(const bf16x8*)(srow + (6 + u) * 32);
#pragma unroll
            for (int u = 0; u < 3; ++u)
                oacc = __builtin_amdgcn_mfma_f32_16x16x32_bf16(af[u], bf[u], oacc, 0, 0, 0);
        }
    }
    __syncthreads();                           // S(int) reads done
    float* red = (float*)S;                    // 8 waves x 64 lanes x f32x4 = 8KB
    *(f32x4*)&red[wv * 256 + l * 4] = oacc;
    __syncthreads();
    if (wv < 2) {
        f32x4 s0 = *(const f32x4*)&red[(0 * 2 + wv) * 256 + l * 4];
        f32x4 s1 = *(const f32x4*)&red[(1 * 2 + wv) * 256 + l * 4];
        f32x4 s2 = *(const f32x4*)&red[(2 * 2 + wv) * 256 + l * 4];
        f32x4 s3 = *(const f32x4*)&red[(3 * 2 + wv) * 256 + l * 4];
        f32x4 sm = (s0 + s1) + (s2 + s3);
#pragma unroll
        for (int r = 0; r < 4; ++r) {
            int oc = wv * 16 + ((l >> 4) << 2) + r;
            if (oc < 18) {
                offL[l & 15][oc] = sm[r] + obv[oc];
            } else if (oc < 27) {
                float z = sm[r] + obv[oc];
                maskL[l & 15][oc - 18] = 1.f / (1.f + expf(-z));
            }
        }
    }
    __syncthreads();                           // offL/maskL ready

    // ---- bilinear params: lane j (<18) computes set (pp=wv*2+j/9, k=j%9) ----
    int pw0i = 0, pw1i = 0, pw2i = 0, pw3i = 0, pa0 = 0, pa1 = 0, pdx = 0;
    if (l < 18) {
        const int p = wv * 2 + l / 9;
        const int k = l - 9 * (l / 9);
        const float offy = offL[p][2 * k];
        const float offx = offL[p][2 * k + 1];
        const float m    = maskL[p][k];
        const float py = (float)(hy + (k / 3 - 1) * dil) + offy;
        const float px = (float)(wx0 + p + (k % 3 - 1) * dil) + offx;
        const float y0f = floorf(py), x0f = floorf(px);
        const float ly = py - y0f, lx = px - x0f;
        const int y0 = (int)y0f, x0 = (int)x0f;
        const float yv0 = (y0 >= 0 && y0 < Hn)      ? 1.f : 0.f;
        const float yv1 = (y0 >= -1 && y0 < Hn - 1) ? 1.f : 0.f;
        const float xv0 = (x0 >= 0 && x0 < Wn)      ? 1.f : 0.f;
        const float xv1 = (x0 >= -1 && x0 < Wn - 1) ? 1.f : 0.f;
        const float wy0 = (1.f - ly) * yv0 * m;
        const float wy1 = ly * yv1 * m;
        const float wxa = (1.f - lx) * xv0;
        const float wxb = lx * xv1;
        pw0i = __float_as_int(wy0 * wxa);
        pw1i = __float_as_int(wy0 * wxb);
        pw2i = __float_as_int(wy1 * wxa);
        pw3i = __float_as_int(wy1 * wxb);
        const int y0c = min(max(y0, 0), Hn - 1), y1c = min(max(y0 + 1, 0), Hn - 1);
        const int x0c = min(max(x0, 0), Wn - 1), x1c = min(max(x0 + 1, 0), Wn - 1);
        pa0 = (basep + y0c * Wn + x0c) * 128;
        pa1 = (basep + y1c * Wn + x1c) * 128;
        pdx = (x1c - x0c) * 128;
    }

    // ---- prefetch first 4 dconv A-frags + epilogue residual ----
    bf16x8 daf[4];
    {
        const short* darow = wbs + (wv * 36) * 512 + l * 8;
#pragma unroll
        for (int u = 0; u < 4; ++u) daf[u] = *(const bf16x8*)(darow + u * 512);
    }
    const int pp  = l & 15;
    const int ocb = wv * 16 + ((l >> 4) << 2);
    uint2 resb;
    if (last) {
        resb = *(const uint2*)&xTb[(pix0 + pp) * 128 + ocb];
    } else {
        const int o = t * 4;
        resb = *(const uint2*)&xTb[(pix0 + (o >> 7)) * 128 + (o & 127)];
    }

    // ---- gather-bil: bf16 source (uint = 2ch), unpack->FMA->pack ----
#pragma unroll
    for (int bch = 0; bch < 6; ++bch) {
        unsigned u00[3], u01[3], u10[3], u11[3];
        float    w00[3], w01[3], w10[3], w11[3];
#pragma unroll
        for (int u = 0; u < 3; ++u) {
            const int i = bch * 3 + u;
            w00[u] = __int_as_float(__builtin_amdgcn_readlane(pw0i, i));
            w01[u] = __int_as_float(__builtin_amdgcn_readlane(pw1i, i));
            w10[u] = __int_as_float(__builtin_amdgcn_readlane(pw2i, i));
            w11[u] = __int_as_float(__builtin_amdgcn_readlane(pw3i, i));
            const int a00 = __builtin_amdgcn_readlane(pa0, i);
            const int a11 = __builtin_amdgcn_readlane(pa1, i);
            const int dxk = __builtin_amdgcn_readlane(pdx, i);
            const unsigned short* xp = xTb + a00;
            const unsigned short* xq = xTb + a11;
            u00[u] = ((const unsigned*)xp)[l];
            u01[u] = ((const unsigned*)(xp + dxk))[l];
            u10[u] = ((const unsigned*)(xq - dxk))[l];
            u11[u] = ((const unsigned*)xq)[l];
        }
#pragma unroll
        for (int u = 0; u < 3; ++u) {
            const int i  = bch * 3 + u;
            const int di = i / 9;
            const int k  = i - di * 9;
            const int ppw = wv * 2 + di;
            float s0 = w00[u] * bflo(u00[u]) + w01[u] * bflo(u01[u])
                     + w10[u] * bflo(u10[u]) + w11[u] * bflo(u11[u]);
            float s1 = w00[u] * bfhi(u00[u]) + w01[u] * bfhi(u01[u])
                     + w10[u] * bfhi(u10[u]) + w11[u] * bfhi(u11[u]);
            ((unsigned*)&S[ppw * KPAD + k * 128])[l] = pack2(s0, s1);
        }
    }
    __syncthreads();

    // ---- dconv GEMM: batch 0 partly from prefetched regs ----
    f32x4 dacc = {0.f, 0.f, 0.f, 0.f};
    {
        const short* darow = wbs + (wv * 36) * 512 + l * 8;
        const short* srow  = &S[(l & 15) * KPAD + ((l >> 4) * 8)];
        {   // batch 0: u0..3 from daf, u4..5 from global
            bf16x8 af45[2], bf[6];
            af45[0] = *(const bf16x8*)(darow + 4 * 512);
            af45[1] = *(const bf16x8*)(darow + 5 * 512);
#pragma unroll
            for (int u = 0; u < 6; ++u) bf[u] = *(const bf16x8*)(srow + u * 32);
#pragma unroll
            for (int u = 0; u < 4; ++u)
                dacc = __builtin_amdgcn_mfma_f32_16x16x32_bf16(daf[u], bf[u], dacc, 0, 0, 0);
            dacc = __builtin_amdgcn_mfma_f32_16x16x32_bf16(af45[0], bf[4], dacc, 0, 0, 0);
            dacc = __builtin_amdgcn_mfma_f32_16x16x32_bf16(af45[1], bf[5], dacc, 0, 0, 0);
        }
#pragma unroll
        for (int bch = 1; bch < 6; ++bch) {
            bf16x8 af[6], bf[6];
#pragma unroll
            for (int u = 0; u < 6; ++u) af[u] = *(const bf16x8*)(darow + (bch * 6 + u) * 512);
#pragma unroll
            for (int u = 0; u < 6; ++u) bf[u] = *(const bf16x8*)(srow  + (bch * 6 + u) * 32);
#pragma unroll
            for (int u = 0; u < 6; ++u)
                dacc = __builtin_amdgcn_mfma_f32_16x16x32_bf16(af[u], bf[u], dacc, 0, 0, 0);
        }
    }

    // ---- epilogue: BN + ReLU + residual(bf16) ----
    if (last) {
        const float rs[4] = {bflo(resb.x), bfhi(resb.x), bflo(resb.y), bfhi(resb.y)};
#pragma unroll
        for (int r = 0; r < 4; ++r) {
            const int oc = ocb + r;
            const float sc = gv[oc] * rsqrtf(vv[oc] + EPSn);
            float y = (dacc[r] - mv[oc]) * sc + bv[oc];
            y = fmaxf(y, 0.f) + rs[r];
            outC[b * CHWn + oc * HWn + sp0 + pp] = y;
        }
    } else {
        __syncthreads();                       // all S reads done; alias O on S
        float* O = (float*)S;                  // O[16][132]
#pragma unroll
        for (int r = 0; r < 4; ++r) {
            const int oc = ocb + r;
            const float sc = gv[oc] * rsqrtf(vv[oc] + EPSn);
            float y = (dacc[r] - mv[oc]) * sc + bv[oc];
            O[pp * 132 + oc] = fmaxf(y, 0.f);
        }
        __syncthreads();
        const int o  = t * 4;                  // 0..2047
        const int qp = o >> 7, qc = o & 127;
        f32x4 yv = *(f32x4*)&O[qp * 132 + qc];
        yv[0] += bflo(resb.x);
        yv[1] += bfhi(resb.x);
        yv[2] += bflo(resb.y);
        yv[3] += bfhi(resb.y);
        uint2 pk;
        pk.x = pack2(yv[0], yv[1]);
        pk.y = pack2(yv[2], yv[3]);
        *(uint2*)&outTb[(pix0 + qp) * 128 + qc] = pk;
    }
}

extern "C" void kernel_launch(void* const* d_in, const int* in_sizes, int n_in,
                              void* d_out, int out_size, void* d_ws, size_t ws_size,
                              hipStream_t stream) {
    (void)in_sizes; (void)n_in; (void)out_size; (void)ws_size;

    const float* hu = (const float*)d_in[0];

    short* wbs  = (short*)d_ws;                          // 3 * 147456 shorts
    short* owbs = wbs + 3 * Cn * KCn;                    // 3 * 36864 shorts
    unsigned short* T0b = (unsigned short*)(owbs + 3 * 32 * KCn);  // Bn*CHWn
    unsigned short* T1b = T0b + Bn * CHWn;

    // prep: transpose + stage-1 weights only
    prep_s1<<<1008, 256, 0, stream>>>(
        hu, (const float*)d_in[3], (const float*)d_in[1], wbs, owbs, T0b);

    const int dils[3] = {2, 4, 8};
    const unsigned short* insb[3] = {T0b, T1b, T0b};
    unsigned short* outsb[3] = {T1b, T0b, nullptr};

    for (int i = 0; i < 3; ++i) {
        const float* obv = (const float*)d_in[2 + 7 * i];
        const float* gv  = (const float*)d_in[4 + 7 * i];
        const float* bv  = (const float*)d_in[5 + 7 * i];
        const float* mv  = (const float*)d_in[6 + 7 * i];
        const float* vv  = (const float*)d_in[7 + 7 * i];
        const int last = (i == 2);

        // stages 0,1 carry 360 extra blocks shuffling the NEXT stage's weights
        const int nblk = last ? 1152 : 1152 + 360;
        const float* wnext  = last ? nullptr : (const float*)d_in[3 + 7 * (i + 1)];
        const float* ownext = last ? nullptr : (const float*)d_in[1 + 7 * (i + 1)];
        short* wbs_next  = last ? nullptr : wbs  + (i + 1) * Cn * KCn;
        short* owbs_next = last ? nullptr : owbs + (i + 1) * 32 * KCn;

        fused_stage<<<nblk, 512, 0, stream>>>(
            insb[i], wbs + i * Cn * KCn, owbs + i * 32 * KCn, obv,
            gv, bv, mv, vv, outsb[i],
            last ? (float*)d_out : nullptr, dils[i], last,
            wnext, ownext, wbs_next, owbs_next);
    }
}